// Round 8
// baseline (254.805 us; speedup 1.0000x reference)
//
#include <hip/hip_runtime.h>
#include <math.h>

#define Bx 256
#define Nx 128
#define Dx 512
#define Mx (Bx * Nx)      // 32768 rows
#define NTYPES 6
#define NSTATS 8
#define LN_EPS 1e-5f
#define CAP 8192          // max compacted masked rows (true ~4915)

typedef __attribute__((ext_vector_type(8))) short frag8;   // 8 bf16 (4 VGPRs)
typedef __attribute__((ext_vector_type(4))) float f32x4;   // 4 fp32 acc

__device__ __forceinline__ unsigned short f2bf(float f) {
    unsigned u = __float_as_uint(f);
    u += 0x7fff + ((u >> 16) & 1);   // RNE
    return (unsigned short)(u >> 16);
}
__device__ __forceinline__ float bf2f(unsigned short s) {
    return __uint_as_float((unsigned)s << 16);
}

#define ASYNC16(g, l) __builtin_amdgcn_global_load_lds(                      \
    (const __attribute__((address_space(1))) void*)(g),                      \
    (__attribute__((address_space(3))) void*)(l), 16, 0, 0)

// stage one 128x32 A-tile + 128x32 B-tile into LDS buffer (4 KB/call x 4)
__device__ __forceinline__ void stage4(const unsigned short* Ag0,
                                       const unsigned short* Ag1,
                                       const unsigned short* Bg0,
                                       const unsigned short* Bg1, int k0,
                                       unsigned short* Asl, unsigned short* Bsl,
                                       int t) {
    ASYNC16(Ag0 + k0, Asl + t * 8);
    ASYNC16(Ag1 + k0, Asl + (t + 256) * 8);
    ASYNC16(Bg0 + k0, Bsl + t * 8);
    ASYNC16(Bg1 + k0, Bsl + (t + 256) * 8);
}

// 16 MFMAs of one 128x128x32 step; aswz = bank-conflict XOR swizzle offset
__device__ __forceinline__ void mfma_step(const unsigned short* Asl,
                                          const unsigned short* Bsl,
                                          int wr, int wcol, int mr, int aswz,
                                          f32x4 acc[4][4]) {
    frag8 a[4], b[4];
#pragma unroll
    for (int i = 0; i < 4; ++i)
        a[i] = *(const frag8*)&Asl[(wr + i * 16 + mr) * 32 + aswz];
#pragma unroll
    for (int j = 0; j < 4; ++j)
        b[j] = *(const frag8*)&Bsl[(wcol + j * 16 + mr) * 32 + aswz];
#pragma unroll
    for (int i = 0; i < 4; ++i)
#pragma unroll
        for (int j = 0; j < 4; ++j)
            acc[i][j] = __builtin_amdgcn_mfma_f32_16x16x32_bf16(
                a[i], b[j], acc[i][j], 0, 0, 0);
}

// ws layout (bytes), total < 86 MB
#define EB_OFF    0ULL          // Eb  bf16 [32768][512]  32 MB
#define U_OFF     33554432ULL   // U   bf16 [32768][512]  32 MB
#define HC_OFF    67108864ULL   // Hc  bf16 [CAP][1024]   16 MB
#define WT_OFF    83886080ULL   // Wtcomb bf16 [1024][512] 1 MB
#define WTC_OFF   84934656ULL   // Wtc    bf16 [512][512] 0.5 MB
#define LIST_OFF  85458944ULL   // list int[32768]
#define CNTS_OFF  85590016ULL   // cnts int[256]
#define PACC_OFF  85591040ULL   // pacc float[256][2]
#define PCORR_OFF 85593088ULL   // pcorr float[256]
#define CNTP_OFF  85594112ULL   // cntp int (memset to 0 first)

// Mega-prep, one dispatch:
// blocks [0,256):     per-batch mask compaction -> list/cnts/cntp
// blocks [256,1024):  3 weight transposes W[k][n] f32 -> Wt[n][k] bf16
// blocks [1024,9216): E f32 -> bf16 (wave per row, 4 rows/block)
__global__ __launch_bounds__(256) void k_prep(
    const float* __restrict__ e, const float* __restrict__ W0,
    const float* __restrict__ W1, const float* __restrict__ W2,
    unsigned short* __restrict__ Eb, unsigned short* __restrict__ Tcmb,
    unsigned short* __restrict__ Tc, const int* __restrict__ m,
    int* __restrict__ list, int* __restrict__ cnts, int* cntp) {
    const int bid = blockIdx.x;
    const int t = threadIdx.x;
    if (bid < 256) {
        const int b = bid;
        const int r = b * Nx + t;
        int v = 0;
        if (t < 128) v = (m[r] != 0) ? 1 : 0;
        const unsigned long long bal = __ballot(v);
        const int wid = t >> 6, lane = t & 63;
        __shared__ int wcnt[2];
        __shared__ int base;
        if (lane == 0 && wid < 2) wcnt[wid] = __popcll(bal);
        __syncthreads();
        const int cnt = wcnt[0] + wcnt[1];
        if (t == 0) {
            base = atomicAdd(cntp, cnt);
            cnts[b] = cnt;
        }
        __syncthreads();
        if (t < 128 && v) {
            const int rank = __popcll(bal & ((1ULL << lane) - 1)) +
                             (wid ? wcnt[0] : 0);
            const int p = base + rank;
            if (p < CAP) list[p] = r;
        }
        return;
    }
    if (bid < 1024) {
        const int lin = (bid - 256) * 256 + t;            // < 196608
        const int mid = lin >> 16;                        // 65536 per matrix
        const int i4  = (lin & 65535) * 4;
        const int n = i4 >> 9, k = i4 & 511;
        const float* W = (mid == 0) ? W0 : (mid == 1) ? W1 : W2;
        unsigned short* T = (mid == 2) ? Tc : (Tcmb + mid * 262144);
        unsigned short o[4];
#pragma unroll
        for (int j = 0; j < 4; ++j) o[j] = f2bf(W[(k + j) * Dx + n]);
        uint2 u;
        u.x = (unsigned)o[0] | ((unsigned)o[1] << 16);
        u.y = (unsigned)o[2] | ((unsigned)o[3] << 16);
        *(uint2*)(T + i4) = u;
        return;
    }
    const int r = (bid - 1024) * 4 + (t >> 6);
    const int lane = t & 63;
    const float4* src = (const float4*)(e + (size_t)r * Dx);
    const float4 a = src[lane * 2];
    const float4 b = src[lane * 2 + 1];
    unsigned short u[8] = {f2bf(a.x), f2bf(a.y), f2bf(a.z), f2bf(a.w),
                           f2bf(b.x), f2bf(b.y), f2bf(b.z), f2bf(b.w)};
    ((uint4*)(Eb + (size_t)r * Dx))[lane] = *(const uint4*)u;
}

// One dispatch, two GEMMs, BK=32, double-buffered async pipeline + XOR swizzle:
// blocks [0,1024):    U = Eb @ Wtc^T  (col-fastest linear grid)
// blocks [1024,1536): Hc = GELU(Eb[list] @ Wtcmb^T + [tb1|sb1]) (indirect gather)
__global__ __launch_bounds__(256) void k_gemms(
    const unsigned short* __restrict__ Eb,
    const unsigned short* __restrict__ Wtc,
    const unsigned short* __restrict__ Wtcmb,
    const float* __restrict__ bias0, const float* __restrict__ bias1,
    unsigned short* __restrict__ U, unsigned short* __restrict__ Hc,
    const int* __restrict__ list, const int* __restrict__ cntp) {
    __shared__ unsigned short As[2][4096];
    __shared__ unsigned short Bs[2][4096];
    const int bid = blockIdx.x;
    const int t = threadIdx.x;
    const unsigned short* Bt;
    unsigned short* C;
    int row0, col0, ldc, head, ra0, ra1;
    if (bid < 1024) {
        row0 = (bid >> 2) << 7;
        col0 = (bid & 3) << 7;
        Bt = Wtc; C = U; ldc = 512; head = 0;
        ra0 = row0 + (t >> 2);
        ra1 = ra0 + 64;
    } else {
        const int b2 = bid - 1024;
        row0 = (b2 >> 3) << 7;
        const int cnt = min(*cntp, CAP);
        if (row0 >= cnt) return;
        col0 = (b2 & 7) << 7;
        Bt = Wtcmb; C = Hc; ldc = 1024; head = 1;
        ra0 = list[min(row0 + (t >> 2), cnt - 1)];
        ra1 = list[min(row0 + 64 + (t >> 2), cnt - 1)];
    }
    const int w = t >> 6, l = t & 63;
    const int wr = (w >> 1) * 64, wcol = (w & 1) * 64;
    const int quad = l >> 4, mr = l & 15;
    // staging: thread t fills physical k-chunk (t&3) of row (t>>2) with global
    // chunk (t&3)^((t>>2)&3); reader fetches logical chunk quad at physical
    // quad^(row&3). Breaks the 64B-stride 8-way bank alias down to 4-way.
    const int gswz = (((t & 3) ^ ((t >> 2) & 3)) - (t & 3)) * 8;
    const int aswz = (quad ^ (mr & 3)) * 8;

    const unsigned short* Ag0 = Eb + (size_t)ra0 * Dx + (t & 3) * 8 + gswz;
    const unsigned short* Ag1 = Eb + (size_t)ra1 * Dx + (t & 3) * 8 + gswz;
    const unsigned short* Bg0 = Bt + (size_t)(col0 + (t >> 2)) * Dx + (t & 3) * 8 + gswz;
    const unsigned short* Bg1 = Bg0 + (size_t)64 * Dx;

    f32x4 acc[4][4] = {};
    stage4(Ag0, Ag1, Bg0, Bg1, 0, As[0], Bs[0], t);
    for (int k0 = 0; k0 < Dx; k0 += 64) {
        __syncthreads();                       // drains buf0 loads
        stage4(Ag0, Ag1, Bg0, Bg1, k0 + 32, As[1], Bs[1], t);
        mfma_step(As[0], Bs[0], wr, wcol, mr, aswz, acc);
        __syncthreads();                       // drains buf1 loads
        if (k0 + 64 < Dx)
            stage4(Ag0, Ag1, Bg0, Bg1, k0 + 64, As[0], Bs[0], t);
        mfma_step(As[1], Bs[1], wr, wcol, mr, aswz, acc);
    }
#pragma unroll
    for (int i = 0; i < 4; ++i)
#pragma unroll
        for (int j = 0; j < 4; ++j)
#pragma unroll
            for (int r = 0; r < 4; ++r) {
                const int row = row0 + wr + i * 16 + quad * 4 + r;
                const int col = col0 + wcol + j * 16 + mr;
                float v = acc[i][j][r];
                if (head) {
                    v += (col < 512) ? bias0[col] : bias1[col - 512];
                    v = 0.5f * v * (1.0f + erff(v * 0.70710678118654752f));
                }
                C[(size_t)row * ldc + col] = f2bf(v);
            }
}

// One dispatch, two epilogues:
// blocks [0,256):   per-batch corr: S = U_b @ E_b^T (pipelined), tanh/diag/SSE
// blocks [256,512): both MLP heads: LN + W2 + CE/MSE over compact list
__global__ __launch_bounds__(256) void k_tail(
    const unsigned short* __restrict__ U,
    const unsigned short* __restrict__ Eb,
    const float* __restrict__ Ct, const int* __restrict__ m,
    const float* __restrict__ cbp, float* __restrict__ pcorr,
    const unsigned short* __restrict__ Hc,
    const float* __restrict__ tg, const float* __restrict__ tbeta,
    const float* __restrict__ tW2, const float* __restrict__ tb2,
    const float* __restrict__ sg, const float* __restrict__ sbeta,
    const float* __restrict__ sW2, const float* __restrict__ sb2,
    const int* __restrict__ list, const int* __restrict__ cntp,
    const int* __restrict__ tgt, const float* __restrict__ stats,
    float* __restrict__ pacc) {
    __shared__ unsigned short As[2][4096];
    __shared__ unsigned short Bs[2][4096];
    __shared__ float mloc[128];
    __shared__ float redf[4][2];
    const int t = threadIdx.x;
    const int w = t >> 6, l = t & 63;

    if (blockIdx.x < 256) {
        const int b = blockIdx.x;
        const int wr = (w >> 1) * 64, wcol = (w & 1) * 64;
        const int quad = l >> 4, mr = l & 15;
        if (t < 128) mloc[t] = (m[b * Nx + t] != 0) ? 1.0f : 0.0f;

        const int gswz = (((t & 3) ^ ((t >> 2) & 3)) - (t & 3)) * 8;
        const int aswz = (quad ^ (mr & 3)) * 8;
        const unsigned short* Ub = U + (size_t)b * Nx * Dx;
        const unsigned short* E  = Eb + (size_t)b * Nx * Dx;
        const unsigned short* Ag0 = Ub + (size_t)(t >> 2) * Dx + (t & 3) * 8 + gswz;
        const unsigned short* Ag1 = Ag0 + (size_t)64 * Dx;
        const unsigned short* Bg0 = E + (size_t)(t >> 2) * Dx + (t & 3) * 8 + gswz;
        const unsigned short* Bg1 = Bg0 + (size_t)64 * Dx;

        f32x4 acc_r[4][4] = {};
        stage4(Ag0, Ag1, Bg0, Bg1, 0, As[0], Bs[0], t);
        for (int k0 = 0; k0 < Dx; k0 += 64) {
            __syncthreads();
            stage4(Ag0, Ag1, Bg0, Bg1, k0 + 32, As[1], Bs[1], t);
            mfma_step(As[0], Bs[0], wr, wcol, mr, aswz, acc_r);
            __syncthreads();
            if (k0 + 64 < Dx)
                stage4(Ag0, Ag1, Bg0, Bg1, k0 + 64, As[0], Bs[0], t);
            mfma_step(As[1], Bs[1], wr, wcol, mr, aswz, acc_r);
        }
        const float cb = cbp[0];
        float lsum = 0.0f;
#pragma unroll
        for (int i = 0; i < 4; ++i)
#pragma unroll
            for (int j = 0; j < 4; ++j)
#pragma unroll
                for (int r = 0; r < 4; ++r) {
                    const int row = wr + i * 16 + quad * 4 + r;
                    const int col = wcol + j * 16 + mr;
                    float c = (row == col) ? 1.0f : tanhf(acc_r[i][j][r] + cb);
                    const float me = fmaxf(mloc[row], mloc[col]);
                    const float d = c - Ct[((size_t)b * Nx + row) * Nx + col];
                    lsum += me * d * d;
                }
#pragma unroll
        for (int off = 32; off > 0; off >>= 1) lsum += __shfl_down(lsum, off);
        if (l == 0) redf[w][0] = lsum;
        __syncthreads();
        if (t == 0) pcorr[b] = redf[0][0] + redf[1][0] + redf[2][0] + redf[3][0];
        return;
    }

    // ---- head2 branch ----
    const int blk = blockIdx.x - 256;
    const int cnt = min(*cntp, CAP);
    float ce_acc = 0.0f, sse_acc = 0.0f;
    for (int idx = blk * 4 + w; idx < cnt; idx += 256 * 4) {
        const int r = list[idx];
        const uint4 ut = ((const uint4*)(Hc + (size_t)idx * 1024))[l];
        const uint4 us = ((const uint4*)(Hc + (size_t)idx * 1024 + 512))[l];
        float a[8], b8[8];
        {
            const unsigned uu[4] = {ut.x, ut.y, ut.z, ut.w};
            const unsigned vv[4] = {us.x, us.y, us.z, us.w};
#pragma unroll
            for (int j = 0; j < 4; ++j) {
                a[2 * j]      = bf2f((unsigned short)(uu[j] & 0xffff));
                a[2 * j + 1]  = bf2f((unsigned short)(uu[j] >> 16));
                b8[2 * j]     = bf2f((unsigned short)(vv[j] & 0xffff));
                b8[2 * j + 1] = bf2f((unsigned short)(vv[j] >> 16));
            }
        }
        float st = 0, qt = 0, ss = 0, qs = 0;
#pragma unroll
        for (int j = 0; j < 8; ++j) {
            st += a[j]; qt += a[j] * a[j];
            ss += b8[j]; qs += b8[j] * b8[j];
        }
#pragma unroll
        for (int off = 32; off > 0; off >>= 1) {
            st += __shfl_xor(st, off); qt += __shfl_xor(qt, off);
            ss += __shfl_xor(ss, off); qs += __shfl_xor(qs, off);
        }
        const float mt = st * (1.0f / Dx);
        const float rt = rsqrtf(qt * (1.0f / Dx) - mt * mt + LN_EPS);
        const float ms = ss * (1.0f / Dx);
        const float rs = rsqrtf(qs * (1.0f / Dx) - ms * ms + LN_EPS);

        const int c0 = l * 8;
        float tp[6] = {}, sp[8] = {};
#pragma unroll
        for (int j = 0; j < 8; ++j) {
            const int c = c0 + j;
            const float nt = (a[j] - mt) * rt * tg[c] + tbeta[c];
#pragma unroll
            for (int k = 0; k < 6; ++k) tp[k] += nt * tW2[c * 6 + k];
            const float ns = (b8[j] - ms) * rs * sg[c] + sbeta[c];
#pragma unroll
            for (int k = 0; k < 8; ++k) sp[k] += ns * sW2[c * 8 + k];
        }
#pragma unroll
        for (int k = 0; k < 6; ++k)
#pragma unroll
            for (int off = 32; off > 0; off >>= 1) tp[k] += __shfl_down(tp[k], off);
#pragma unroll
        for (int k = 0; k < 8; ++k)
#pragma unroll
            for (int off = 32; off > 0; off >>= 1) sp[k] += __shfl_down(sp[k], off);

        if (l == 0) {
            float lg[6];
#pragma unroll
            for (int k = 0; k < 6; ++k) lg[k] = tp[k] + tb2[k];
            float mx = lg[0];
#pragma unroll
            for (int k = 1; k < 6; ++k) mx = fmaxf(mx, lg[k]);
            float se = 0.0f;
#pragma unroll
            for (int k = 0; k < 6; ++k) se += expf(lg[k] - mx);
            ce_acc += -(lg[tgt[r & (Nx - 1)]] - mx - logf(se));
            float sse = 0.0f;
#pragma unroll
            for (int k = 0; k < 8; ++k) {
                const float d = sp[k] + sb2[k] - stats[(size_t)r * NSTATS + k];
                sse += d * d;
            }
            sse_acc += sse;
        }
    }
    if (l == 0) { redf[w][0] = ce_acc; redf[w][1] = sse_acc; }
    __syncthreads();
    if (t == 0) {
        pacc[2 * blk]     = redf[0][0] + redf[1][0] + redf[2][0] + redf[3][0];
        pacc[2 * blk + 1] = redf[0][1] + redf[1][1] + redf[2][1] + redf[3][1];
    }
}

__global__ __launch_bounds__(256) void k_final(
    const float* __restrict__ pacc, const float* __restrict__ pcorr,
    const int* __restrict__ cnts, const int* __restrict__ cntp,
    float* __restrict__ out) {
    const int t = threadIdx.x, w = t >> 6, lane = t & 63;
    float ce = pacc[2 * t], sse = pacc[2 * t + 1], co = pcorr[t];
    const int c = cnts[t];
    float me = (float)(Nx * Nx) - (float)((Nx - c) * (Nx - c));
#pragma unroll
    for (int off = 32; off > 0; off >>= 1) {
        ce += __shfl_down(ce, off);
        sse += __shfl_down(sse, off);
        co += __shfl_down(co, off);
        me += __shfl_down(me, off);
    }
    __shared__ float red[4][4];
    if (lane == 0) {
        red[w][0] = ce; red[w][1] = sse; red[w][2] = co; red[w][3] = me;
    }
    __syncthreads();
    if (t == 0) {
        const float CE = red[0][0] + red[1][0] + red[2][0] + red[3][0];
        const float SSE = red[0][1] + red[1][1] + red[2][1] + red[3][1];
        const float CO = red[0][2] + red[1][2] + red[2][2] + red[3][2];
        const float ME = red[0][3] + red[1][3] + red[2][3] + red[3][3];
        const float nm = fmaxf((float)*cntp, 1.0f);
        const float nme = fmaxf(ME, 1.0f);
        out[0] = CE / nm + SSE / (nm * (float)NSTATS) + 0.5f * CO / nme;
    }
}

extern "C" void kernel_launch(void* const* d_in, const int* in_sizes, int n_in,
                              void* d_out, int out_size, void* d_ws, size_t ws_size,
                              hipStream_t stream) {
    const float* e      = (const float*)d_in[0];
    const int*   mcols  = (const int*)d_in[1];
    const int*   ttgt   = (const int*)d_in[2];
    const float* stats  = (const float*)d_in[3];
    const float* corrT  = (const float*)d_in[4];
    const float* tW1    = (const float*)d_in[5];
    const float* tb1    = (const float*)d_in[6];
    const float* tg     = (const float*)d_in[7];
    const float* tbeta  = (const float*)d_in[8];
    const float* tW2    = (const float*)d_in[9];
    const float* tb2    = (const float*)d_in[10];
    const float* sW1    = (const float*)d_in[11];
    const float* sb1    = (const float*)d_in[12];
    const float* sg     = (const float*)d_in[13];
    const float* sbeta  = (const float*)d_in[14];
    const float* sW2    = (const float*)d_in[15];
    const float* sb2    = (const float*)d_in[16];
    const float* cW     = (const float*)d_in[17];
    const float* cb     = (const float*)d_in[18];
    float* out = (float*)d_out;

    char* ws = (char*)d_ws;
    unsigned short* Eb    = (unsigned short*)(ws + EB_OFF);
    unsigned short* U     = (unsigned short*)(ws + U_OFF);
    unsigned short* Hc    = (unsigned short*)(ws + HC_OFF);
    unsigned short* Wtcmb = (unsigned short*)(ws + WT_OFF);
    unsigned short* Wtc   = (unsigned short*)(ws + WTC_OFF);
    int*   list  = (int*)(ws + LIST_OFF);
    int*   cnts  = (int*)(ws + CNTS_OFF);
    float* pacc  = (float*)(ws + PACC_OFF);
    float* pcorr = (float*)(ws + PCORR_OFF);
    int*   cntp  = (int*)(ws + CNTP_OFF);

    hipMemsetAsync(cntp, 0, sizeof(int), stream);
    k_prep<<<9216, 256, 0, stream>>>(e, tW1, sW1, cW, Eb, Wtcmb, Wtc, mcols,
                                     list, cnts, cntp);
    k_gemms<<<1536, 256, 0, stream>>>(Eb, Wtc, Wtcmb, tb1, sb1, U, Hc, list, cntp);
    k_tail<<<512, 256, 0, stream>>>(U, Eb, corrT, mcols, cb, pcorr,
                                    Hc, tg, tbeta, tW2, tb2, sg, sbeta, sW2, sb2,
                                    list, cntp, ttgt, stats, pacc);
    k_final<<<1, 256, 0, stream>>>(pacc, pcorr, cnts, cntp, out);
}

// Round 9
// 242.579 us; speedup vs baseline: 1.0504x; 1.0504x over previous
//
#include <hip/hip_runtime.h>
#include <math.h>

#define Bx 256
#define Nx 128
#define Dx 512
#define Mx (Bx * Nx)      // 32768 rows
#define NTYPES 6
#define NSTATS 8
#define LN_EPS 1e-5f
#define CAP 8192          // max compacted masked rows (true ~4915)

typedef __attribute__((ext_vector_type(8))) short frag8;   // 8 bf16 (4 VGPRs)
typedef __attribute__((ext_vector_type(4))) float f32x4;   // 4 fp32 acc

__device__ __forceinline__ unsigned short f2bf(float f) {
    unsigned u = __float_as_uint(f);
    u += 0x7fff + ((u >> 16) & 1);   // RNE
    return (unsigned short)(u >> 16);
}
__device__ __forceinline__ float bf2f(unsigned short s) {
    return __uint_as_float((unsigned)s << 16);
}

#define ASYNC16(g, l) __builtin_amdgcn_global_load_lds(                      \
    (const __attribute__((address_space(1))) void*)(g),                      \
    (__attribute__((address_space(3))) void*)(l), 16, 0, 0)

// ws layout (bytes), total < 86 MB
#define EB_OFF    0ULL          // Eb  bf16 [32768][512]  32 MB
#define U_OFF     33554432ULL   // U   bf16 [32768][512]  32 MB
#define HC_OFF    67108864ULL   // Hc  bf16 [CAP][1024]   16 MB
#define WT_OFF    83886080ULL   // Wtcomb bf16 [1024][512] 1 MB
#define WTC_OFF   84934656ULL   // Wtc    bf16 [512][512] 0.5 MB
#define LIST_OFF  85458944ULL   // list int[32768]
#define CNTS_OFF  85590016ULL   // cnts int[256]
#define PACC_OFF  85591040ULL   // pacc float[256][2]
#define PCORR_OFF 85593088ULL   // pcorr float[512]
#define CNTP_OFF  85595136ULL   // cntp int (memset to 0 first)

// Mega-prep, one dispatch:
// blocks [0,256):     per-batch mask compaction -> list/cnts/cntp
// blocks [256,1024):  3 weight transposes W[k][n] f32 -> Wt[n][k] bf16
// blocks [1024,9216): E f32 -> bf16 (wave per row, 4 rows/block)
__global__ __launch_bounds__(256) void k_prep(
    const float* __restrict__ e, const float* __restrict__ W0,
    const float* __restrict__ W1, const float* __restrict__ W2,
    unsigned short* __restrict__ Eb, unsigned short* __restrict__ Tcmb,
    unsigned short* __restrict__ Tc, const int* __restrict__ m,
    int* __restrict__ list, int* __restrict__ cnts, int* cntp) {
    const int bid = blockIdx.x;
    const int t = threadIdx.x;
    if (bid < 256) {
        const int b = bid;
        const int r = b * Nx + t;
        int v = 0;
        if (t < 128) v = (m[r] != 0) ? 1 : 0;
        const unsigned long long bal = __ballot(v);
        const int wid = t >> 6, lane = t & 63;
        __shared__ int wcnt[2];
        __shared__ int base;
        if (lane == 0 && wid < 2) wcnt[wid] = __popcll(bal);
        __syncthreads();
        const int cnt = wcnt[0] + wcnt[1];
        if (t == 0) {
            base = atomicAdd(cntp, cnt);
            cnts[b] = cnt;
        }
        __syncthreads();
        if (t < 128 && v) {
            const int rank = __popcll(bal & ((1ULL << lane) - 1)) +
                             (wid ? wcnt[0] : 0);
            const int p = base + rank;
            if (p < CAP) list[p] = r;
        }
        return;
    }
    if (bid < 1024) {
        const int lin = (bid - 256) * 256 + t;            // < 196608
        const int mid = lin >> 16;                        // 65536 per matrix
        const int i4  = (lin & 65535) * 4;
        const int n = i4 >> 9, k = i4 & 511;
        const float* W = (mid == 0) ? W0 : (mid == 1) ? W1 : W2;
        unsigned short* T = (mid == 2) ? Tc : (Tcmb + mid * 262144);
        unsigned short o[4];
#pragma unroll
        for (int j = 0; j < 4; ++j) o[j] = f2bf(W[(k + j) * Dx + n]);
        uint2 u;
        u.x = (unsigned)o[0] | ((unsigned)o[1] << 16);
        u.y = (unsigned)o[2] | ((unsigned)o[3] << 16);
        *(uint2*)(T + i4) = u;
        return;
    }
    const int r = (bid - 1024) * 4 + (t >> 6);
    const int lane = t & 63;
    const float4* src = (const float4*)(e + (size_t)r * Dx);
    const float4 a = src[lane * 2];
    const float4 b = src[lane * 2 + 1];
    unsigned short u[8] = {f2bf(a.x), f2bf(a.y), f2bf(a.z), f2bf(a.w),
                           f2bf(b.x), f2bf(b.y), f2bf(b.z), f2bf(b.w)};
    ((uint4*)(Eb + (size_t)r * Dx))[lane] = *(const uint4*)u;
}

// One dispatch, two GEMMs. Tile 64 rows x 128 cols, BK=32, single buffer.
// Small acc (2x4 f32x4 = 32 AGPR) -> ~5 waves/SIMD residency.
// blocks [0,2048):    U = Eb @ Wtc^T       (col-fastest: bid&3)
// blocks [2048,3072): Hc = GELU(Eb[list] @ Wtcmb^T + [tb1|sb1])
__global__ __launch_bounds__(256) void k_gemms(
    const unsigned short* __restrict__ Eb,
    const unsigned short* __restrict__ Wtc,
    const unsigned short* __restrict__ Wtcmb,
    const float* __restrict__ bias0, const float* __restrict__ bias1,
    unsigned short* __restrict__ U, unsigned short* __restrict__ Hc,
    const int* __restrict__ list, const int* __restrict__ cntp) {
    __shared__ unsigned short As[64 * 32];    // 4 KB
    __shared__ unsigned short Bs[128 * 32];   // 8 KB
    const int bid = blockIdx.x;
    const int t = threadIdx.x;
    const unsigned short* Bt;
    unsigned short* C;
    int row0, col0, ldc, head, ra0;
    if (bid < 2048) {
        row0 = (bid >> 2) << 6;
        col0 = (bid & 3) << 7;
        Bt = Wtc; C = U; ldc = 512; head = 0;
        ra0 = row0 + (t >> 2);
    } else {
        const int b2 = bid - 2048;
        row0 = (b2 >> 3) << 6;
        const int cnt = min(*cntp, CAP);
        if (row0 >= cnt) return;
        col0 = (b2 & 7) << 7;
        Bt = Wtcmb; C = Hc; ldc = 1024; head = 1;
        ra0 = list[min(row0 + (t >> 2), cnt - 1)];
    }
    const int w = t >> 6, l = t & 63;
    const int wr = (w >> 1) * 32, wcol = (w & 1) * 64;
    const int quad = l >> 4, mr = l & 15;

    const unsigned short* Ag0 = Eb + (size_t)ra0 * Dx + (t & 3) * 8;
    const unsigned short* Bg0 = Bt + (size_t)(col0 + (t >> 2)) * Dx + (t & 3) * 8;
    const unsigned short* Bg1 = Bg0 + (size_t)64 * Dx;

    f32x4 acc[2][4] = {};
    for (int k0 = 0; k0 < Dx; k0 += 32) {
        __syncthreads();
        ASYNC16(Ag0 + k0, As + t * 8);
        ASYNC16(Bg0 + k0, Bs + t * 8);
        ASYNC16(Bg1 + k0, Bs + (t + 256) * 8);
        __syncthreads();
        frag8 a[2], b[4];
#pragma unroll
        for (int i = 0; i < 2; ++i)
            a[i] = *(const frag8*)&As[(wr + i * 16 + mr) * 32 + quad * 8];
#pragma unroll
        for (int j = 0; j < 4; ++j)
            b[j] = *(const frag8*)&Bs[(wcol + j * 16 + mr) * 32 + quad * 8];
#pragma unroll
        for (int i = 0; i < 2; ++i)
#pragma unroll
            for (int j = 0; j < 4; ++j)
                acc[i][j] = __builtin_amdgcn_mfma_f32_16x16x32_bf16(
                    a[i], b[j], acc[i][j], 0, 0, 0);
    }
#pragma unroll
    for (int i = 0; i < 2; ++i)
#pragma unroll
        for (int j = 0; j < 4; ++j)
#pragma unroll
            for (int r = 0; r < 4; ++r) {
                const int row = row0 + wr + i * 16 + quad * 4 + r;
                const int col = col0 + wcol + j * 16 + mr;
                float v = acc[i][j][r];
                if (head) {
                    v += (col < 512) ? bias0[col] : bias1[col - 512];
                    v = 0.5f * v * (1.0f + erff(v * 0.70710678118654752f));
                }
                C[(size_t)row * ldc + col] = f2bf(v);
            }
}

// One dispatch, two epilogues:
// blocks [0,512):   per-batch corr halves: S[64x128] = U_b[half] @ E_b^T,
//                   tanh/diag/masked-SSE -> pcorr[bid]
// blocks [512,768): both MLP heads: LN + W2 + CE/MSE over compact list
__global__ __launch_bounds__(256) void k_tail(
    const unsigned short* __restrict__ U,
    const unsigned short* __restrict__ Eb,
    const float* __restrict__ Ct, const int* __restrict__ m,
    const float* __restrict__ cbp, float* __restrict__ pcorr,
    const unsigned short* __restrict__ Hc,
    const float* __restrict__ tg, const float* __restrict__ tbeta,
    const float* __restrict__ tW2, const float* __restrict__ tb2,
    const float* __restrict__ sg, const float* __restrict__ sbeta,
    const float* __restrict__ sW2, const float* __restrict__ sb2,
    const int* __restrict__ list, const int* __restrict__ cntp,
    const int* __restrict__ tgt, const float* __restrict__ stats,
    float* __restrict__ pacc) {
    __shared__ unsigned short As[64 * 32];
    __shared__ unsigned short Bs[128 * 32];
    __shared__ float mloc[128];
    __shared__ float redf[4][2];
    const int t = threadIdx.x;
    const int w = t >> 6, l = t & 63;

    if (blockIdx.x < 512) {
        const int b = blockIdx.x >> 1;
        const int row0 = (blockIdx.x & 1) << 6;     // U row half
        const int wr = (w >> 1) * 32, wcol = (w & 1) * 64;
        const int quad = l >> 4, mr = l & 15;
        if (t < 128) mloc[t] = (m[b * Nx + t] != 0) ? 1.0f : 0.0f;

        const unsigned short* Ub = U + (size_t)b * Nx * Dx;
        const unsigned short* E  = Eb + (size_t)b * Nx * Dx;
        const unsigned short* Ag0 = Ub + (size_t)(row0 + (t >> 2)) * Dx + (t & 3) * 8;
        const unsigned short* Bg0 = E + (size_t)(t >> 2) * Dx + (t & 3) * 8;
        const unsigned short* Bg1 = Bg0 + (size_t)64 * Dx;

        f32x4 acc_r[2][4] = {};
        for (int k0 = 0; k0 < Dx; k0 += 32) {
            __syncthreads();
            ASYNC16(Ag0 + k0, As + t * 8);
            ASYNC16(Bg0 + k0, Bs + t * 8);
            ASYNC16(Bg1 + k0, Bs + (t + 256) * 8);
            __syncthreads();
            frag8 a[2], bfr[4];
#pragma unroll
            for (int i = 0; i < 2; ++i)
                a[i] = *(const frag8*)&As[(wr + i * 16 + mr) * 32 + quad * 8];
#pragma unroll
            for (int j = 0; j < 4; ++j)
                bfr[j] = *(const frag8*)&Bs[(wcol + j * 16 + mr) * 32 + quad * 8];
#pragma unroll
            for (int i = 0; i < 2; ++i)
#pragma unroll
                for (int j = 0; j < 4; ++j)
                    acc_r[i][j] = __builtin_amdgcn_mfma_f32_16x16x32_bf16(
                        a[i], bfr[j], acc_r[i][j], 0, 0, 0);
        }
        const float cb = cbp[0];
        float lsum = 0.0f;
#pragma unroll
        for (int i = 0; i < 2; ++i)
#pragma unroll
            for (int j = 0; j < 4; ++j)
#pragma unroll
                for (int r = 0; r < 4; ++r) {
                    const int row = row0 + wr + i * 16 + quad * 4 + r;
                    const int col = wcol + j * 16 + mr;
                    float c = (row == col) ? 1.0f : tanhf(acc_r[i][j][r] + cb);
                    const float me = fmaxf(mloc[row], mloc[col]);
                    const float d = c - Ct[((size_t)b * Nx + row) * Nx + col];
                    lsum += me * d * d;
                }
#pragma unroll
        for (int off = 32; off > 0; off >>= 1) lsum += __shfl_down(lsum, off);
        if (l == 0) redf[w][0] = lsum;
        __syncthreads();
        if (t == 0) pcorr[blockIdx.x] = redf[0][0] + redf[1][0] + redf[2][0] + redf[3][0];
        return;
    }

    // ---- head2 branch ----
    const int blk = blockIdx.x - 512;
    const int cnt = min(*cntp, CAP);
    float ce_acc = 0.0f, sse_acc = 0.0f;
    for (int idx = blk * 4 + w; idx < cnt; idx += 256 * 4) {
        const int r = list[idx];
        const uint4 ut = ((const uint4*)(Hc + (size_t)idx * 1024))[l];
        const uint4 us = ((const uint4*)(Hc + (size_t)idx * 1024 + 512))[l];
        float a[8], b8[8];
        {
            const unsigned uu[4] = {ut.x, ut.y, ut.z, ut.w};
            const unsigned vv[4] = {us.x, us.y, us.z, us.w};
#pragma unroll
            for (int j = 0; j < 4; ++j) {
                a[2 * j]      = bf2f((unsigned short)(uu[j] & 0xffff));
                a[2 * j + 1]  = bf2f((unsigned short)(uu[j] >> 16));
                b8[2 * j]     = bf2f((unsigned short)(vv[j] & 0xffff));
                b8[2 * j + 1] = bf2f((unsigned short)(vv[j] >> 16));
            }
        }
        float st = 0, qt = 0, ss = 0, qs = 0;
#pragma unroll
        for (int j = 0; j < 8; ++j) {
            st += a[j]; qt += a[j] * a[j];
            ss += b8[j]; qs += b8[j] * b8[j];
        }
#pragma unroll
        for (int off = 32; off > 0; off >>= 1) {
            st += __shfl_xor(st, off); qt += __shfl_xor(qt, off);
            ss += __shfl_xor(ss, off); qs += __shfl_xor(qs, off);
        }
        const float mt = st * (1.0f / Dx);
        const float rt = rsqrtf(qt * (1.0f / Dx) - mt * mt + LN_EPS);
        const float ms = ss * (1.0f / Dx);
        const float rs = rsqrtf(qs * (1.0f / Dx) - ms * ms + LN_EPS);

        const int c0 = l * 8;
        float tp[6] = {}, sp[8] = {};
#pragma unroll
        for (int j = 0; j < 8; ++j) {
            const int c = c0 + j;
            const float nt = (a[j] - mt) * rt * tg[c] + tbeta[c];
#pragma unroll
            for (int k = 0; k < 6; ++k) tp[k] += nt * tW2[c * 6 + k];
            const float ns = (b8[j] - ms) * rs * sg[c] + sbeta[c];
#pragma unroll
            for (int k = 0; k < 8; ++k) sp[k] += ns * sW2[c * 8 + k];
        }
#pragma unroll
        for (int k = 0; k < 6; ++k)
#pragma unroll
            for (int off = 32; off > 0; off >>= 1) tp[k] += __shfl_down(tp[k], off);
#pragma unroll
        for (int k = 0; k < 8; ++k)
#pragma unroll
            for (int off = 32; off > 0; off >>= 1) sp[k] += __shfl_down(sp[k], off);

        if (l == 0) {
            float lg[6];
#pragma unroll
            for (int k = 0; k < 6; ++k) lg[k] = tp[k] + tb2[k];
            float mx = lg[0];
#pragma unroll
            for (int k = 1; k < 6; ++k) mx = fmaxf(mx, lg[k]);
            float se = 0.0f;
#pragma unroll
            for (int k = 0; k < 6; ++k) se += expf(lg[k] - mx);
            ce_acc += -(lg[tgt[r & (Nx - 1)]] - mx - logf(se));
            float sse = 0.0f;
#pragma unroll
            for (int k = 0; k < 8; ++k) {
                const float d = sp[k] + sb2[k] - stats[(size_t)r * NSTATS + k];
                sse += d * d;
            }
            sse_acc += sse;
        }
    }
    if (l == 0) { redf[w][0] = ce_acc; redf[w][1] = sse_acc; }
    __syncthreads();
    if (t == 0) {
        pacc[2 * blk]     = redf[0][0] + redf[1][0] + redf[2][0] + redf[3][0];
        pacc[2 * blk + 1] = redf[0][1] + redf[1][1] + redf[2][1] + redf[3][1];
    }
}

__global__ __launch_bounds__(256) void k_final(
    const float* __restrict__ pacc, const float* __restrict__ pcorr,
    const int* __restrict__ cnts, const int* __restrict__ cntp,
    float* __restrict__ out) {
    const int t = threadIdx.x, w = t >> 6, lane = t & 63;
    float ce = pacc[2 * t], sse = pacc[2 * t + 1];
    float co = pcorr[t] + pcorr[t + 256];
    const int c = cnts[t];
    float me = (float)(Nx * Nx) - (float)((Nx - c) * (Nx - c));
#pragma unroll
    for (int off = 32; off > 0; off >>= 1) {
        ce += __shfl_down(ce, off);
        sse += __shfl_down(sse, off);
        co += __shfl_down(co, off);
        me += __shfl_down(me, off);
    }
    __shared__ float red[4][4];
    if (lane == 0) {
        red[w][0] = ce; red[w][1] = sse; red[w][2] = co; red[w][3] = me;
    }
    __syncthreads();
    if (t == 0) {
        const float CE = red[0][0] + red[1][0] + red[2][0] + red[3][0];
        const float SSE = red[0][1] + red[1][1] + red[2][1] + red[3][1];
        const float CO = red[0][2] + red[1][2] + red[2][2] + red[3][2];
        const float ME = red[0][3] + red[1][3] + red[2][3] + red[3][3];
        const float nm = fmaxf((float)*cntp, 1.0f);
        const float nme = fmaxf(ME, 1.0f);
        out[0] = CE / nm + SSE / (nm * (float)NSTATS) + 0.5f * CO / nme;
    }
}

extern "C" void kernel_launch(void* const* d_in, const int* in_sizes, int n_in,
                              void* d_out, int out_size, void* d_ws, size_t ws_size,
                              hipStream_t stream) {
    const float* e      = (const float*)d_in[0];
    const int*   mcols  = (const int*)d_in[1];
    const int*   ttgt   = (const int*)d_in[2];
    const float* stats  = (const float*)d_in[3];
    const float* corrT  = (const float*)d_in[4];
    const float* tW1    = (const float*)d_in[5];
    const float* tb1    = (const float*)d_in[6];
    const float* tg     = (const float*)d_in[7];
    const float* tbeta  = (const float*)d_in[8];
    const float* tW2    = (const float*)d_in[9];
    const float* tb2    = (const float*)d_in[10];
    const float* sW1    = (const float*)d_in[11];
    const float* sb1    = (const float*)d_in[12];
    const float* sg     = (const float*)d_in[13];
    const float* sbeta  = (const float*)d_in[14];
    const float* sW2    = (const float*)d_in[15];
    const float* sb2    = (const float*)d_in[16];
    const float* cW     = (const float*)d_in[17];
    const float* cb     = (const float*)d_in[18];
    float* out = (float*)d_out;

    char* ws = (char*)d_ws;
    unsigned short* Eb    = (unsigned short*)(ws + EB_OFF);
    unsigned short* U     = (unsigned short*)(ws + U_OFF);
    unsigned short* Hc    = (unsigned short*)(ws + HC_OFF);
    unsigned short* Wtcmb = (unsigned short*)(ws + WT_OFF);
    unsigned short* Wtc   = (unsigned short*)(ws + WTC_OFF);
    int*   list  = (int*)(ws + LIST_OFF);
    int*   cnts  = (int*)(ws + CNTS_OFF);
    float* pacc  = (float*)(ws + PACC_OFF);
    float* pcorr = (float*)(ws + PCORR_OFF);
    int*   cntp  = (int*)(ws + CNTP_OFF);

    hipMemsetAsync(cntp, 0, sizeof(int), stream);
    k_prep<<<9216, 256, 0, stream>>>(e, tW1, sW1, cW, Eb, Wtcmb, Wtc, mcols,
                                     list, cnts, cntp);
    k_gemms<<<3072, 256, 0, stream>>>(Eb, Wtc, Wtcmb, tb1, sb1, U, Hc, list, cntp);
    k_tail<<<768, 256, 0, stream>>>(U, Eb, corrT, mcols, cb, pcorr,
                                    Hc, tg, tbeta, tW2, tb2, sg, sbeta, sW2, sb2,
                                    list, cntp, ttgt, stats, pacc);
    k_final<<<1, 256, 0, stream>>>(pacc, pcorr, cnts, cntp, out);
}